// Round 9
// baseline (193.752 us; speedup 1.0000x reference)
//
#include <hip/hip_runtime.h>
#include <math.h>

#define NN 50000
#define NE 800000
#define DD 128
#define HH 128
#define BN_EPS 1e-3f
#define SCB 196   // ceil(NN/256)

typedef _Float16 f16x8 __attribute__((ext_vector_type(8)));
typedef float f32x4 __attribute__((ext_vector_type(4)));

__device__ __forceinline__ float gelu_f(float x) {
    return 0.5f * x * (1.0f + erff(x * 0.70710678118654752f));
}

// ---- fold BN into transposed f16 weights + f32 bias (all 4 layers) ---------
struct WArgs {
    const float *W, *g, *bb, *m, *v, *bias;
    _Float16* wt; float* bs; int K;
};

__global__ __launch_bounds__(256)
void weights_all_kernel(WArgs a0, WArgs a1, WArgs a2, WArgs a3)
{
    __shared__ float red[256];
    const int which = blockIdx.x >> 7;
    const int n = blockIdx.x & 127;
    WArgs a = a0;
    if (which == 1) a = a1;
    else if (which == 2) a = a2;
    else if (which == 3) a = a3;
    const int t = threadIdx.x;
    float part = 0.0f;
    for (int k = t; k < a.K; k += 256) {
        float sc = a.g[k] * rsqrtf(a.v[k] + BN_EPS);
        float sh = a.bb[k] - a.m[k] * sc;
        float wv = a.W[(long long)k * HH + n];
        a.wt[(long long)n * a.K + k] = (_Float16)(wv * sc);
        part += sh * wv;
    }
    red[t] = part;
    __syncthreads();
    for (int s = 128; s > 0; s >>= 1) {
        if (t < s) red[t] += red[t + s];
        __syncthreads();
    }
    if (t == 0) a.bs[n] = a.bias[n] + red[0];
}

// ---- prep FFN (MFMA, reg-resident B): 32 rows/block; also emits xh ---------
__global__ __launch_bounds__(256, 4)
void prep_kernel(const float* __restrict__ x,
                 const _Float16* __restrict__ wt0, const float* __restrict__ bs0,
                 const _Float16* __restrict__ wt1, const float* __restrict__ bs1,
                 _Float16* __restrict__ msg, _Float16* __restrict__ xh)
{
    __shared__ __align__(16) _Float16 smem[32 * DD];   // 8 KB, xs then ys
    const int tid = threadIdx.x;
    const int w = tid >> 6, lane = tid & 63;
    const int row0 = blockIdx.x * 32;
    const int cl = lane & 15;
    const int kg = lane >> 4;

    // layer-0 B fragments: this wave's 32 cols, all K
    f16x8 b0[4][2];
#pragma unroll
    for (int kc = 0; kc < 4; ++kc)
#pragma unroll
        for (int ct = 0; ct < 2; ++ct) {
            int col = w * 32 + ct * 16 + cl;
            b0[kc][ct] = *reinterpret_cast<const f16x8*>(&wt0[(long long)col * DD + kc * 32 + kg * 8]);
        }

    // stage x -> smem (f16, swizzled) + write xh (linear, coalesced)
    for (int i = tid; i < 32 * (DD / 8); i += 256) {
        int r = i >> 4, k8 = i & 15;
        int row = row0 + r;
        f16x8 h;
        if (row < NN) {
            const float4* p = reinterpret_cast<const float4*>(&x[(long long)row * DD + k8 * 8]);
            float4 u0 = p[0], u1 = p[1];
            h[0] = (_Float16)u0.x; h[1] = (_Float16)u0.y; h[2] = (_Float16)u0.z; h[3] = (_Float16)u0.w;
            h[4] = (_Float16)u1.x; h[5] = (_Float16)u1.y; h[6] = (_Float16)u1.z; h[7] = (_Float16)u1.w;
            *reinterpret_cast<f16x8*>(&xh[(long long)row * DD + k8 * 8]) = h;
        } else {
#pragma unroll
            for (int q = 0; q < 8; ++q) h[q] = (_Float16)0.0f;
        }
        int slot = (r * 16 + k8) ^ (r & 7);
        *reinterpret_cast<f16x8*>(&smem[slot * 8]) = h;
    }
    __syncthreads();

    const f32x4 zero = {0.0f, 0.0f, 0.0f, 0.0f};
    f32x4 acc[2][2];
#pragma unroll
    for (int rt = 0; rt < 2; ++rt)
#pragma unroll
        for (int ct = 0; ct < 2; ++ct) acc[rt][ct] = zero;

#pragma unroll
    for (int kc = 0; kc < 4; ++kc) {
        int k8 = kc * 4 + kg;
#pragma unroll
        for (int rt = 0; rt < 2; ++rt) {
            int rA = rt * 16 + cl;
            int slot = (rA * 16 + k8) ^ (rA & 7);
            f16x8 a = *reinterpret_cast<const f16x8*>(&smem[slot * 8]);
#pragma unroll
            for (int ct = 0; ct < 2; ++ct)
                acc[rt][ct] = __builtin_amdgcn_mfma_f32_16x16x32_f16(a, b0[kc][ct], acc[rt][ct], 0, 0, 0);
        }
    }

    // layer-1 B fragments (b0 now dead; latency overlaps epilogue)
    f16x8 b1[4][2];
#pragma unroll
    for (int kc = 0; kc < 4; ++kc)
#pragma unroll
        for (int ct = 0; ct < 2; ++ct) {
            int col = w * 32 + ct * 16 + cl;
            b1[kc][ct] = *reinterpret_cast<const f16x8*>(&wt1[(long long)col * HH + kc * 32 + kg * 8]);
        }

    __syncthreads();   // all xs reads done; smem becomes ys

#pragma unroll
    for (int ct = 0; ct < 2; ++ct) {
        int col = w * 32 + ct * 16 + cl;
        float bias = bs0[col];
#pragma unroll
        for (int rt = 0; rt < 2; ++rt)
#pragma unroll
            for (int rr = 0; rr < 4; ++rr) {
                int r = rt * 16 + kg * 4 + rr;
                float vv = gelu_f(acc[rt][ct][rr] + bias);
                int slot = (r * 16 + (col >> 3)) ^ (r & 7);
                smem[slot * 8 + (col & 7)] = (_Float16)vv;
            }
    }
    __syncthreads();

    f32x4 acc2[2][2];
#pragma unroll
    for (int rt = 0; rt < 2; ++rt)
#pragma unroll
        for (int ct = 0; ct < 2; ++ct) acc2[rt][ct] = zero;

#pragma unroll
    for (int kc = 0; kc < 4; ++kc) {
        int k8 = kc * 4 + kg;
#pragma unroll
        for (int rt = 0; rt < 2; ++rt) {
            int rA = rt * 16 + cl;
            int slot = (rA * 16 + k8) ^ (rA & 7);
            f16x8 a = *reinterpret_cast<const f16x8*>(&smem[slot * 8]);
#pragma unroll
            for (int ct = 0; ct < 2; ++ct)
                acc2[rt][ct] = __builtin_amdgcn_mfma_f32_16x16x32_f16(a, b1[kc][ct], acc2[rt][ct], 0, 0, 0);
        }
    }

#pragma unroll
    for (int ct = 0; ct < 2; ++ct) {
        int col = w * 32 + ct * 16 + cl;
        float bias = bs1[col];
#pragma unroll
        for (int rt = 0; rt < 2; ++rt)
#pragma unroll
            for (int rr = 0; rr < 4; ++rr) {
                int row = row0 + rt * 16 + kg * 4 + rr;
                if (row < NN)
                    msg[(long long)row * HH + col] = (_Float16)gelu_f(acc2[rt][ct][rr] + bias);
            }
    }
}

// ---- CSR build -------------------------------------------------------------
__global__ __launch_bounds__(256)
void degpos_kernel(const int* __restrict__ edges, int* __restrict__ deg,
                   int* __restrict__ pos)
{
    int e = blockIdx.x * 256 + threadIdx.x;
    if (e < NE) pos[e] = atomicAdd(&deg[edges[e]], 1);
}

__global__ __launch_bounds__(256)
void scan_partial_kernel(const int* __restrict__ deg, int* __restrict__ part)
{
    __shared__ int red[256];
    int t = threadIdx.x;
    int i = blockIdx.x * 256 + t;
    red[t] = (i < NN) ? deg[i] : 0;
    __syncthreads();
    for (int s = 128; s > 0; s >>= 1) {
        if (t < s) red[t] += red[t + s];
        __syncthreads();
    }
    if (t == 0) part[blockIdx.x] = red[0];
}

__global__ __launch_bounds__(256)
void scan_offsets_kernel(const int* __restrict__ part, int* __restrict__ boff)
{
    __shared__ int s[256];
    int t = threadIdx.x;
    s[t] = (t < SCB) ? part[t] : 0;
    __syncthreads();
    for (int off = 1; off < 256; off <<= 1) {
        int v = (t >= off) ? s[t - off] : 0;
        __syncthreads();
        s[t] += v;
        __syncthreads();
    }
    boff[t] = (t == 0) ? 0 : s[t - 1];
}

__global__ __launch_bounds__(256)
void scan_write_kernel(const int* __restrict__ deg, const int* __restrict__ boff,
                       int* __restrict__ rowptr)
{
    __shared__ int s[256];
    int t = threadIdx.x, b = blockIdx.x;
    int i = b * 256 + t;
    int v = (i < NN) ? deg[i] : 0;
    s[t] = v;
    __syncthreads();
    for (int off = 1; off < 256; off <<= 1) {
        int u = (t >= off) ? s[t - off] : 0;
        __syncthreads();
        s[t] += u;
        __syncthreads();
    }
    if (i < NN) rowptr[i] = boff[b] + (s[t] - v);
    if (b == SCB - 1 && t == 255) rowptr[NN] = boff[b] + s[255];
}

__global__ __launch_bounds__(256)
void fill_kernel(const int* __restrict__ edges, const float* __restrict__ ew,
                 const int* __restrict__ rowptr, const int* __restrict__ pos,
                 int2* __restrict__ rec)
{
    int e = blockIdx.x * 256 + threadIdx.x;
    if (e >= NE) return;
    int d = edges[e];
    int idx = rowptr[d] + pos[e];
    int2 r;
    r.x = edges[NE + e];
    r.y = __float_as_int(ew[e]);
    rec[idx] = r;
}

// ---- fused gather + update FFN: 32 rows/block ------------------------------
__global__ __launch_bounds__(256, 4)
void upd_kernel(const _Float16* __restrict__ xh,
                const int* __restrict__ rowptr, const int2* __restrict__ rec,
                const _Float16* __restrict__ msg,
                const _Float16* __restrict__ wt2, const float* __restrict__ bs2,
                const _Float16* __restrict__ wt3, const float* __restrict__ bs3,
                float* __restrict__ out)
{
    __shared__ __align__(16) _Float16 smem[32 * 256];   // 16 KB, xs then ys
    const int tid = threadIdx.x;
    const int w = tid >> 6, lane = tid & 63;
    const int row0 = blockIdx.x * 32;
    const int cl = lane & 15;
    const int kg = lane >> 4;

    // layer-0 B fragments (this wave's 32 cols, all K=256) — issued early
    f16x8 b0[8][2];
#pragma unroll
    for (int kc = 0; kc < 8; ++kc)
#pragma unroll
        for (int ct = 0; ct < 2; ++ct) {
            int col = w * 32 + ct * 16 + cl;
            b0[kc][ct] = *reinterpret_cast<const f16x8*>(&wt2[(long long)col * 256 + kc * 32 + kg * 8]);
        }

    // stage xh -> smem cols 0..127 (k8 = 0..15)
    for (int i = tid; i < 32 * 16; i += 256) {
        int r = i >> 4, k8 = i & 15;
        int row = row0 + r;
        f16x8 h;
        if (row < NN) {
            h = *reinterpret_cast<const f16x8*>(&xh[(long long)row * DD + k8 * 8]);
        } else {
#pragma unroll
            for (int q = 0; q < 8; ++q) h[q] = (_Float16)0.0f;
        }
        int slot = (r * 32 + k8) ^ (r & 7);
        *reinterpret_cast<f16x8*>(&smem[slot * 8]) = h;
    }

    // fused gather: wave covers 8 rows in 2 halves (4 rows x 16 lanes each)
    {
        int sub = lane >> 4, l16 = lane & 15;
#pragma unroll
        for (int half = 0; half < 2; ++half) {
            int r = half * 16 + w * 4 + sub;     // 0..31 across waves+halves
            int node = row0 + r;
            int beg = 0, end = 0;
            if (node < NN) { beg = rowptr[node]; end = rowptr[node + 1]; }
            float acc[8];
#pragma unroll
            for (int q = 0; q < 8; ++q) acc[q] = 0.0f;
            for (int j = beg; j < end; ++j) {
                int2 rc = rec[j];
                int src = rc.x;
                float wv = __int_as_float(rc.y);
                f16x8 m = *reinterpret_cast<const f16x8*>(&msg[(long long)src * HH + l16 * 8]);
#pragma unroll
                for (int q = 0; q < 8; ++q) acc[q] += (float)m[q] * wv;
            }
            float inv = (end > beg) ? 1.0f / (float)(end - beg) : 0.0f;
            f16x8 o;
#pragma unroll
            for (int q = 0; q < 8; ++q) o[q] = (_Float16)(acc[q] * inv);
            int k8 = 16 + l16;
            int slot = (r * 32 + k8) ^ (r & 7);
            *reinterpret_cast<f16x8*>(&smem[slot * 8]) = o;
        }
    }
    __syncthreads();

    const f32x4 zero = {0.0f, 0.0f, 0.0f, 0.0f};
    f32x4 acc[2][2];
#pragma unroll
    for (int rt = 0; rt < 2; ++rt)
#pragma unroll
        for (int ct = 0; ct < 2; ++ct) acc[rt][ct] = zero;

#pragma unroll
    for (int kc = 0; kc < 8; ++kc) {
        int k8 = kc * 4 + kg;
#pragma unroll
        for (int rt = 0; rt < 2; ++rt) {
            int rA = rt * 16 + cl;
            int slot = (rA * 32 + k8) ^ (rA & 7);
            f16x8 a = *reinterpret_cast<const f16x8*>(&smem[slot * 8]);
#pragma unroll
            for (int ct = 0; ct < 2; ++ct)
                acc[rt][ct] = __builtin_amdgcn_mfma_f32_16x16x32_f16(a, b0[kc][ct], acc[rt][ct], 0, 0, 0);
        }
    }

    // layer-1 B fragments (b0 dead; loads overlap epilogue)
    f16x8 b1[4][2];
#pragma unroll
    for (int kc = 0; kc < 4; ++kc)
#pragma unroll
        for (int ct = 0; ct < 2; ++ct) {
            int col = w * 32 + ct * 16 + cl;
            b1[kc][ct] = *reinterpret_cast<const f16x8*>(&wt3[(long long)col * HH + kc * 32 + kg * 8]);
        }

    __syncthreads();   // xs reads done; smem becomes ys

#pragma unroll
    for (int ct = 0; ct < 2; ++ct) {
        int col = w * 32 + ct * 16 + cl;
        float bias = bs2[col];
#pragma unroll
        for (int rt = 0; rt < 2; ++rt)
#pragma unroll
            for (int rr = 0; rr < 4; ++rr) {
                int r = rt * 16 + kg * 4 + rr;
                float vv = gelu_f(acc[rt][ct][rr] + bias);
                int slot = (r * 16 + (col >> 3)) ^ (r & 7);
                smem[slot * 8 + (col & 7)] = (_Float16)vv;
            }
    }
    __syncthreads();

    f32x4 acc2[2][2];
#pragma unroll
    for (int rt = 0; rt < 2; ++rt)
#pragma unroll
        for (int ct = 0; ct < 2; ++ct) acc2[rt][ct] = zero;

#pragma unroll
    for (int kc = 0; kc < 4; ++kc) {
        int k8 = kc * 4 + kg;
#pragma unroll
        for (int rt = 0; rt < 2; ++rt) {
            int rA = rt * 16 + cl;
            int slot = (rA * 16 + k8) ^ (rA & 7);
            f16x8 a = *reinterpret_cast<const f16x8*>(&smem[slot * 8]);
#pragma unroll
            for (int ct = 0; ct < 2; ++ct)
                acc2[rt][ct] = __builtin_amdgcn_mfma_f32_16x16x32_f16(a, b1[kc][ct], acc2[rt][ct], 0, 0, 0);
        }
    }

#pragma unroll
    for (int ct = 0; ct < 2; ++ct) {
        int col = w * 32 + ct * 16 + cl;
        float bias = bs3[col];
#pragma unroll
        for (int rt = 0; rt < 2; ++rt)
#pragma unroll
            for (int rr = 0; rr < 4; ++rr) {
                int row = row0 + rt * 16 + kg * 4 + rr;
                if (row < NN)
                    out[(long long)row * HH + col] = gelu_f(acc2[rt][ct][rr] + bias);
            }
    }
}

extern "C" void kernel_launch(void* const* d_in, const int* in_sizes, int n_in,
                              void* d_out, int out_size, void* d_ws, size_t ws_size,
                              hipStream_t stream) {
    const float* node_repr = (const float*)d_in[0];
    const int*   edges     = (const int*)d_in[1];
    const float* ew        = (const float*)d_in[2];

    const float* prep_bn0_g = (const float*)d_in[3];
    const float* prep_bn0_b = (const float*)d_in[4];
    const float* prep_bn0_m = (const float*)d_in[5];
    const float* prep_bn0_v = (const float*)d_in[6];
    const float* prep_W0    = (const float*)d_in[7];
    const float* prep_b0    = (const float*)d_in[8];
    const float* prep_bn1_g = (const float*)d_in[9];
    const float* prep_bn1_b = (const float*)d_in[10];
    const float* prep_bn1_m = (const float*)d_in[11];
    const float* prep_bn1_v = (const float*)d_in[12];
    const float* prep_W1    = (const float*)d_in[13];
    const float* prep_b1    = (const float*)d_in[14];

    const float* upd_bn0_g = (const float*)d_in[15];
    const float* upd_bn0_b = (const float*)d_in[16];
    const float* upd_bn0_m = (const float*)d_in[17];
    const float* upd_bn0_v = (const float*)d_in[18];
    const float* upd_W0    = (const float*)d_in[19];
    const float* upd_b0    = (const float*)d_in[20];
    const float* upd_bn1_g = (const float*)d_in[21];
    const float* upd_bn1_b = (const float*)d_in[22];
    const float* upd_bn1_m = (const float*)d_in[23];
    const float* upd_bn1_v = (const float*)d_in[24];
    const float* upd_W1    = (const float*)d_in[25];
    const float* upd_b1    = (const float*)d_in[26];

    // workspace layout
    _Float16* msg  = (_Float16*)d_ws;                 // NN*HH
    _Float16* xh   = msg + (size_t)NN * HH;           // NN*DD
    _Float16* wt0  = xh + (size_t)NN * DD;            // 128*128
    _Float16* wt1  = wt0 + 128 * 128;                 // 128*128
    _Float16* wt2  = wt1 + 128 * 128;                 // 128*256
    _Float16* wt3  = wt2 + 128 * 256;                 // 128*128
    float* bs0 = (float*)(wt3 + 128 * 128);
    float* bs1 = bs0 + 128;
    float* bs2 = bs1 + 128;
    float* bs3 = bs2 + 128;
    int* deg    = (int*)(bs3 + 128);                  // NN
    int* rowptr = deg + NN;                           // NN+1
    int* part   = rowptr + NN + 1;                    // 256
    int* boff   = part + 256;                         // 256
    int* pos    = boff + 256;                         // NE
    int2* rec   = (int2*)(pos + NE);                  // NE (8B each)

    hipMemsetAsync(deg, 0, (size_t)NN * sizeof(int), stream);

    WArgs a0 = {prep_W0, prep_bn0_g, prep_bn0_b, prep_bn0_m, prep_bn0_v, prep_b0, wt0, bs0, DD};
    WArgs a1 = {prep_W1, prep_bn1_g, prep_bn1_b, prep_bn1_m, prep_bn1_v, prep_b1, wt1, bs1, HH};
    WArgs a2 = {upd_W0, upd_bn0_g, upd_bn0_b, upd_bn0_m, upd_bn0_v, upd_b0, wt2, bs2, DD + HH};
    WArgs a3 = {upd_W1, upd_bn1_g, upd_bn1_b, upd_bn1_m, upd_bn1_v, upd_b1, wt3, bs3, HH};
    weights_all_kernel<<<512, 256, 0, stream>>>(a0, a1, a2, a3);

    int nblk = (NN + 31) / 32;   // 1563
    prep_kernel<<<nblk, 256, 0, stream>>>(node_repr, wt0, bs0, wt1, bs1, msg, xh);

    int eblk = (NE + 255) / 256;
    degpos_kernel<<<eblk, 256, 0, stream>>>(edges, deg, pos);
    scan_partial_kernel<<<SCB, 256, 0, stream>>>(deg, part);
    scan_offsets_kernel<<<1, 256, 0, stream>>>(part, boff);
    scan_write_kernel<<<SCB, 256, 0, stream>>>(deg, boff, rowptr);
    fill_kernel<<<eblk, 256, 0, stream>>>(edges, ew, rowptr, pos, rec);

    upd_kernel<<<nblk, 256, 0, stream>>>(xh, rowptr, rec, msg, wt2, bs2, wt3, bs3,
                                         (float*)d_out);
}

// Round 10
// 175.164 us; speedup vs baseline: 1.1061x; 1.1061x over previous
//
#include <hip/hip_runtime.h>
#include <math.h>

#define NN 50000
#define NE 800000
#define DD 128
#define HH 128
#define BN_EPS 1e-3f
#define SCB 196   // ceil(NN/256)

typedef _Float16 f16x8 __attribute__((ext_vector_type(8)));
typedef float f32x4 __attribute__((ext_vector_type(4)));

__device__ __forceinline__ float gelu_f(float x) {
    return 0.5f * x * (1.0f + erff(x * 0.70710678118654752f));
}

// ---- fold BN into transposed f16 weights + f32 bias (all 4 layers) ---------
struct WArgs {
    const float *W, *g, *bb, *m, *v, *bias;
    _Float16* wt; float* bs; int K;
};

__global__ __launch_bounds__(256)
void weights_all_kernel(WArgs a0, WArgs a1, WArgs a2, WArgs a3)
{
    __shared__ float red[256];
    const int which = blockIdx.x >> 7;
    const int n = blockIdx.x & 127;
    WArgs a = a0;
    if (which == 1) a = a1;
    else if (which == 2) a = a2;
    else if (which == 3) a = a3;
    const int t = threadIdx.x;
    float part = 0.0f;
    for (int k = t; k < a.K; k += 256) {
        float sc = a.g[k] * rsqrtf(a.v[k] + BN_EPS);
        float sh = a.bb[k] - a.m[k] * sc;
        float wv = a.W[(long long)k * HH + n];
        a.wt[(long long)n * a.K + k] = (_Float16)(wv * sc);
        part += sh * wv;
    }
    red[t] = part;
    __syncthreads();
    for (int s = 128; s > 0; s >>= 1) {
        if (t < s) red[t] += red[t + s];
        __syncthreads();
    }
    if (t == 0) a.bs[n] = a.bias[n] + red[0];
}

// ---- prep FFN (MFMA, reg-resident B): 32 rows/block; also emits xh ---------
__global__ __launch_bounds__(256, 4)
void prep_kernel(const float* __restrict__ x,
                 const _Float16* __restrict__ wt0, const float* __restrict__ bs0,
                 const _Float16* __restrict__ wt1, const float* __restrict__ bs1,
                 _Float16* __restrict__ msg, _Float16* __restrict__ xh)
{
    __shared__ __align__(16) _Float16 smem[32 * DD];   // 8 KB, xs then ys
    const int tid = threadIdx.x;
    const int w = tid >> 6, lane = tid & 63;
    const int row0 = blockIdx.x * 32;
    const int cl = lane & 15;
    const int kg = lane >> 4;

    // layer-0 B fragments: this wave's 32 cols, all K
    f16x8 b0[4][2];
#pragma unroll
    for (int kc = 0; kc < 4; ++kc)
#pragma unroll
        for (int ct = 0; ct < 2; ++ct) {
            int col = w * 32 + ct * 16 + cl;
            b0[kc][ct] = *reinterpret_cast<const f16x8*>(&wt0[(long long)col * DD + kc * 32 + kg * 8]);
        }

    // stage x -> smem (f16, swizzled) + write xh (linear, coalesced)
    for (int i = tid; i < 32 * (DD / 8); i += 256) {
        int r = i >> 4, k8 = i & 15;
        int row = row0 + r;
        f16x8 h;
        if (row < NN) {
            const float4* p = reinterpret_cast<const float4*>(&x[(long long)row * DD + k8 * 8]);
            float4 u0 = p[0], u1 = p[1];
            h[0] = (_Float16)u0.x; h[1] = (_Float16)u0.y; h[2] = (_Float16)u0.z; h[3] = (_Float16)u0.w;
            h[4] = (_Float16)u1.x; h[5] = (_Float16)u1.y; h[6] = (_Float16)u1.z; h[7] = (_Float16)u1.w;
            *reinterpret_cast<f16x8*>(&xh[(long long)row * DD + k8 * 8]) = h;
        } else {
#pragma unroll
            for (int q = 0; q < 8; ++q) h[q] = (_Float16)0.0f;
        }
        int slot = (r * 16 + k8) ^ (r & 7);
        *reinterpret_cast<f16x8*>(&smem[slot * 8]) = h;
    }
    __syncthreads();

    const f32x4 zero = {0.0f, 0.0f, 0.0f, 0.0f};
    f32x4 acc[2][2];
#pragma unroll
    for (int rt = 0; rt < 2; ++rt)
#pragma unroll
        for (int ct = 0; ct < 2; ++ct) acc[rt][ct] = zero;

#pragma unroll
    for (int kc = 0; kc < 4; ++kc) {
        int k8 = kc * 4 + kg;
#pragma unroll
        for (int rt = 0; rt < 2; ++rt) {
            int rA = rt * 16 + cl;
            int slot = (rA * 16 + k8) ^ (rA & 7);
            f16x8 a = *reinterpret_cast<const f16x8*>(&smem[slot * 8]);
#pragma unroll
            for (int ct = 0; ct < 2; ++ct)
                acc[rt][ct] = __builtin_amdgcn_mfma_f32_16x16x32_f16(a, b0[kc][ct], acc[rt][ct], 0, 0, 0);
        }
    }

    // layer-1 B fragments (b0 now dead; latency overlaps epilogue)
    f16x8 b1[4][2];
#pragma unroll
    for (int kc = 0; kc < 4; ++kc)
#pragma unroll
        for (int ct = 0; ct < 2; ++ct) {
            int col = w * 32 + ct * 16 + cl;
            b1[kc][ct] = *reinterpret_cast<const f16x8*>(&wt1[(long long)col * HH + kc * 32 + kg * 8]);
        }

    __syncthreads();   // all xs reads done; smem becomes ys

#pragma unroll
    for (int ct = 0; ct < 2; ++ct) {
        int col = w * 32 + ct * 16 + cl;
        float bias = bs0[col];
#pragma unroll
        for (int rt = 0; rt < 2; ++rt)
#pragma unroll
            for (int rr = 0; rr < 4; ++rr) {
                int r = rt * 16 + kg * 4 + rr;
                float vv = gelu_f(acc[rt][ct][rr] + bias);
                int slot = (r * 16 + (col >> 3)) ^ (r & 7);
                smem[slot * 8 + (col & 7)] = (_Float16)vv;
            }
    }
    __syncthreads();

    f32x4 acc2[2][2];
#pragma unroll
    for (int rt = 0; rt < 2; ++rt)
#pragma unroll
        for (int ct = 0; ct < 2; ++ct) acc2[rt][ct] = zero;

#pragma unroll
    for (int kc = 0; kc < 4; ++kc) {
        int k8 = kc * 4 + kg;
#pragma unroll
        for (int rt = 0; rt < 2; ++rt) {
            int rA = rt * 16 + cl;
            int slot = (rA * 16 + k8) ^ (rA & 7);
            f16x8 a = *reinterpret_cast<const f16x8*>(&smem[slot * 8]);
#pragma unroll
            for (int ct = 0; ct < 2; ++ct)
                acc2[rt][ct] = __builtin_amdgcn_mfma_f32_16x16x32_f16(a, b1[kc][ct], acc2[rt][ct], 0, 0, 0);
        }
    }

#pragma unroll
    for (int ct = 0; ct < 2; ++ct) {
        int col = w * 32 + ct * 16 + cl;
        float bias = bs1[col];
#pragma unroll
        for (int rt = 0; rt < 2; ++rt)
#pragma unroll
            for (int rr = 0; rr < 4; ++rr) {
                int row = row0 + rt * 16 + kg * 4 + rr;
                if (row < NN)
                    msg[(long long)row * HH + col] = (_Float16)gelu_f(acc2[rt][ct][rr] + bias);
            }
    }
}

// ---- CSR build -------------------------------------------------------------
__global__ __launch_bounds__(256)
void degpos_kernel(const int* __restrict__ edges, int* __restrict__ deg,
                   int* __restrict__ pos)
{
    int e = blockIdx.x * 256 + threadIdx.x;
    if (e < NE) pos[e] = atomicAdd(&deg[edges[e]], 1);
}

__global__ __launch_bounds__(256)
void scan_partial_kernel(const int* __restrict__ deg, int* __restrict__ part)
{
    __shared__ int red[256];
    int t = threadIdx.x;
    int i = blockIdx.x * 256 + t;
    red[t] = (i < NN) ? deg[i] : 0;
    __syncthreads();
    for (int s = 128; s > 0; s >>= 1) {
        if (t < s) red[t] += red[t + s];
        __syncthreads();
    }
    if (t == 0) part[blockIdx.x] = red[0];
}

__global__ __launch_bounds__(256)
void scan_offsets_kernel(const int* __restrict__ part, int* __restrict__ boff)
{
    __shared__ int s[256];
    int t = threadIdx.x;
    s[t] = (t < SCB) ? part[t] : 0;
    __syncthreads();
    for (int off = 1; off < 256; off <<= 1) {
        int v = (t >= off) ? s[t - off] : 0;
        __syncthreads();
        s[t] += v;
        __syncthreads();
    }
    boff[t] = (t == 0) ? 0 : s[t - 1];
}

__global__ __launch_bounds__(256)
void scan_write_kernel(const int* __restrict__ deg, const int* __restrict__ boff,
                       int* __restrict__ rowptr)
{
    __shared__ int s[256];
    int t = threadIdx.x, b = blockIdx.x;
    int i = b * 256 + t;
    int v = (i < NN) ? deg[i] : 0;
    s[t] = v;
    __syncthreads();
    for (int off = 1; off < 256; off <<= 1) {
        int u = (t >= off) ? s[t - off] : 0;
        __syncthreads();
        s[t] += u;
        __syncthreads();
    }
    if (i < NN) rowptr[i] = boff[b] + (s[t] - v);
    if (b == SCB - 1 && t == 255) rowptr[NN] = boff[b] + s[255];
}

__global__ __launch_bounds__(256)
void fill_kernel(const int* __restrict__ edges, const float* __restrict__ ew,
                 const int* __restrict__ rowptr, const int* __restrict__ pos,
                 int2* __restrict__ rec)
{
    int e = blockIdx.x * 256 + threadIdx.x;
    if (e >= NE) return;
    int d = edges[e];
    int idx = rowptr[d] + pos[e];
    int2 r;
    r.x = edges[NE + e];
    r.y = __float_as_int(ew[e]);
    rec[idx] = r;
}

// ---- gather-aggregate: 4 nodes per wave, f16x8 per lane --------------------
__global__ __launch_bounds__(256)
void gather_kernel(const int* __restrict__ rowptr, const int2* __restrict__ rec,
                   const _Float16* __restrict__ msg, _Float16* __restrict__ aggh)
{
    int gwave = (blockIdx.x * 256 + threadIdx.x) >> 6;
    int lane = threadIdx.x & 63;
    int sub = lane >> 4, l16 = lane & 15;
    int node = gwave * 4 + sub;
    if (node >= NN) return;
    int beg = rowptr[node], end = rowptr[node + 1];
    float acc[8];
#pragma unroll
    for (int q = 0; q < 8; ++q) acc[q] = 0.0f;
    for (int j = beg; j < end; ++j) {
        int2 rc = rec[j];
        int src = rc.x;
        float w = __int_as_float(rc.y);
        f16x8 m = *reinterpret_cast<const f16x8*>(&msg[(long long)src * HH + l16 * 8]);
#pragma unroll
        for (int q = 0; q < 8; ++q) acc[q] += (float)m[q] * w;
    }
    float inv = (end > beg) ? 1.0f / (float)(end - beg) : 0.0f;
    f16x8 o;
#pragma unroll
    for (int q = 0; q < 8; ++q) o[q] = (_Float16)(acc[q] * inv);
    *reinterpret_cast<f16x8*>(&aggh[(long long)node * HH + l16 * 8]) = o;
}

// ---- update FFN (MFMA, reg-resident B): 32 rows/block, K=256, f16 inputs ---
__global__ __launch_bounds__(256, 4)
void upd_kernel(const _Float16* __restrict__ xh, const _Float16* __restrict__ aggh,
                const _Float16* __restrict__ wt2, const float* __restrict__ bs2,
                const _Float16* __restrict__ wt3, const float* __restrict__ bs3,
                float* __restrict__ out)
{
    const int KK = DD + HH;  // 256
    __shared__ __align__(16) _Float16 smem[32 * 256];   // 16 KB, xs then ys
    const int tid = threadIdx.x;
    const int w = tid >> 6, lane = tid & 63;
    const int row0 = blockIdx.x * 32;
    const int cl = lane & 15;
    const int kg = lane >> 4;

    // layer-0 B fragments (this wave's 32 cols, all K=256)
    f16x8 b0[8][2];
#pragma unroll
    for (int kc = 0; kc < 8; ++kc)
#pragma unroll
        for (int ct = 0; ct < 2; ++ct) {
            int col = w * 32 + ct * 16 + cl;
            b0[kc][ct] = *reinterpret_cast<const f16x8*>(&wt2[(long long)col * 256 + kc * 32 + kg * 8]);
        }

    // stage concat(xh, aggh) -> smem (f16, swizzled)
    for (int i = tid; i < 32 * (KK / 8); i += 256) {
        int r = i >> 5, k8 = i & 31;
        int row = row0 + r;
        f16x8 h;
        if (row < NN) {
            if (k8 < 16) {
                h = *reinterpret_cast<const f16x8*>(&xh[(long long)row * DD + k8 * 8]);
            } else {
                h = *reinterpret_cast<const f16x8*>(&aggh[(long long)row * HH + (k8 - 16) * 8]);
            }
        } else {
#pragma unroll
            for (int q = 0; q < 8; ++q) h[q] = (_Float16)0.0f;
        }
        int slot = (r * 32 + k8) ^ (r & 7);
        *reinterpret_cast<f16x8*>(&smem[slot * 8]) = h;
    }
    __syncthreads();

    const f32x4 zero = {0.0f, 0.0f, 0.0f, 0.0f};
    f32x4 acc[2][2];
#pragma unroll
    for (int rt = 0; rt < 2; ++rt)
#pragma unroll
        for (int ct = 0; ct < 2; ++ct) acc[rt][ct] = zero;

#pragma unroll
    for (int kc = 0; kc < 8; ++kc) {
        int k8 = kc * 4 + kg;
#pragma unroll
        for (int rt = 0; rt < 2; ++rt) {
            int rA = rt * 16 + cl;
            int slot = (rA * 32 + k8) ^ (rA & 7);
            f16x8 a = *reinterpret_cast<const f16x8*>(&smem[slot * 8]);
#pragma unroll
            for (int ct = 0; ct < 2; ++ct)
                acc[rt][ct] = __builtin_amdgcn_mfma_f32_16x16x32_f16(a, b0[kc][ct], acc[rt][ct], 0, 0, 0);
        }
    }

    // layer-1 B fragments (b0 dead; loads overlap epilogue)
    f16x8 b1[4][2];
#pragma unroll
    for (int kc = 0; kc < 4; ++kc)
#pragma unroll
        for (int ct = 0; ct < 2; ++ct) {
            int col = w * 32 + ct * 16 + cl;
            b1[kc][ct] = *reinterpret_cast<const f16x8*>(&wt3[(long long)col * HH + kc * 32 + kg * 8]);
        }

    __syncthreads();   // xs reads done; smem becomes ys

#pragma unroll
    for (int ct = 0; ct < 2; ++ct) {
        int col = w * 32 + ct * 16 + cl;
        float bias = bs2[col];
#pragma unroll
        for (int rt = 0; rt < 2; ++rt)
#pragma unroll
            for (int rr = 0; rr < 4; ++rr) {
                int r = rt * 16 + kg * 4 + rr;
                float vv = gelu_f(acc[rt][ct][rr] + bias);
                int slot = (r * 16 + (col >> 3)) ^ (r & 7);
                smem[slot * 8 + (col & 7)] = (_Float16)vv;
            }
    }
    __syncthreads();

    f32x4 acc2[2][2];
#pragma unroll
    for (int rt = 0; rt < 2; ++rt)
#pragma unroll
        for (int ct = 0; ct < 2; ++ct) acc2[rt][ct] = zero;

#pragma unroll
    for (int kc = 0; kc < 4; ++kc) {
        int k8 = kc * 4 + kg;
#pragma unroll
        for (int rt = 0; rt < 2; ++rt) {
            int rA = rt * 16 + cl;
            int slot = (rA * 16 + k8) ^ (rA & 7);
            f16x8 a = *reinterpret_cast<const f16x8*>(&smem[slot * 8]);
#pragma unroll
            for (int ct = 0; ct < 2; ++ct)
                acc2[rt][ct] = __builtin_amdgcn_mfma_f32_16x16x32_f16(a, b1[kc][ct], acc2[rt][ct], 0, 0, 0);
        }
    }

#pragma unroll
    for (int ct = 0; ct < 2; ++ct) {
        int col = w * 32 + ct * 16 + cl;
        float bias = bs3[col];
#pragma unroll
        for (int rt = 0; rt < 2; ++rt)
#pragma unroll
            for (int rr = 0; rr < 4; ++rr) {
                int row = row0 + rt * 16 + kg * 4 + rr;
                if (row < NN)
                    out[(long long)row * HH + col] = gelu_f(acc2[rt][ct][rr] + bias);
            }
    }
}

extern "C" void kernel_launch(void* const* d_in, const int* in_sizes, int n_in,
                              void* d_out, int out_size, void* d_ws, size_t ws_size,
                              hipStream_t stream) {
    const float* node_repr = (const float*)d_in[0];
    const int*   edges     = (const int*)d_in[1];
    const float* ew        = (const float*)d_in[2];

    const float* prep_bn0_g = (const float*)d_in[3];
    const float* prep_bn0_b = (const float*)d_in[4];
    const float* prep_bn0_m = (const float*)d_in[5];
    const float* prep_bn0_v = (const float*)d_in[6];
    const float* prep_W0    = (const float*)d_in[7];
    const float* prep_b0    = (const float*)d_in[8];
    const float* prep_bn1_g = (const float*)d_in[9];
    const float* prep_bn1_b = (const float*)d_in[10];
    const float* prep_bn1_m = (const float*)d_in[11];
    const float* prep_bn1_v = (const float*)d_in[12];
    const float* prep_W1    = (const float*)d_in[13];
    const float* prep_b1    = (const float*)d_in[14];

    const float* upd_bn0_g = (const float*)d_in[15];
    const float* upd_bn0_b = (const float*)d_in[16];
    const float* upd_bn0_m = (const float*)d_in[17];
    const float* upd_bn0_v = (const float*)d_in[18];
    const float* upd_W0    = (const float*)d_in[19];
    const float* upd_b0    = (const float*)d_in[20];
    const float* upd_bn1_g = (const float*)d_in[21];
    const float* upd_bn1_b = (const float*)d_in[22];
    const float* upd_bn1_m = (const float*)d_in[23];
    const float* upd_bn1_v = (const float*)d_in[24];
    const float* upd_W1    = (const float*)d_in[25];
    const float* upd_b1    = (const float*)d_in[26];

    // workspace layout
    _Float16* msg  = (_Float16*)d_ws;                 // NN*HH
    _Float16* aggh = msg + (size_t)NN * HH;           // NN*HH
    _Float16* xh   = aggh + (size_t)NN * HH;          // NN*DD
    _Float16* wt0  = xh + (size_t)NN * DD;            // 128*128
    _Float16* wt1  = wt0 + 128 * 128;                 // 128*128
    _Float16* wt2  = wt1 + 128 * 128;                 // 128*256
    _Float16* wt3  = wt2 + 128 * 256;                 // 128*128
    float* bs0 = (float*)(wt3 + 128 * 128);
    float* bs1 = bs0 + 128;
    float* bs2 = bs1 + 128;
    float* bs3 = bs2 + 128;
    int* deg    = (int*)(bs3 + 128);                  // NN
    int* rowptr = deg + NN;                           // NN+1
    int* part   = rowptr + NN + 1;                    // 256
    int* boff   = part + 256;                         // 256
    int* pos    = boff + 256;                         // NE
    int2* rec   = (int2*)(pos + NE);                  // NE (8B each)

    hipMemsetAsync(deg, 0, (size_t)NN * sizeof(int), stream);

    WArgs a0 = {prep_W0, prep_bn0_g, prep_bn0_b, prep_bn0_m, prep_bn0_v, prep_b0, wt0, bs0, DD};
    WArgs a1 = {prep_W1, prep_bn1_g, prep_bn1_b, prep_bn1_m, prep_bn1_v, prep_b1, wt1, bs1, HH};
    WArgs a2 = {upd_W0, upd_bn0_g, upd_bn0_b, upd_bn0_m, upd_bn0_v, upd_b0, wt2, bs2, DD + HH};
    WArgs a3 = {upd_W1, upd_bn1_g, upd_bn1_b, upd_bn1_m, upd_bn1_v, upd_b1, wt3, bs3, HH};
    weights_all_kernel<<<512, 256, 0, stream>>>(a0, a1, a2, a3);

    int nblk = (NN + 31) / 32;   // 1563
    prep_kernel<<<nblk, 256, 0, stream>>>(node_repr, wt0, bs0, wt1, bs1, msg, xh);

    int eblk = (NE + 255) / 256;
    degpos_kernel<<<eblk, 256, 0, stream>>>(edges, deg, pos);
    scan_partial_kernel<<<SCB, 256, 0, stream>>>(deg, part);
    scan_offsets_kernel<<<1, 256, 0, stream>>>(part, boff);
    scan_write_kernel<<<SCB, 256, 0, stream>>>(deg, boff, rowptr);
    fill_kernel<<<eblk, 256, 0, stream>>>(edges, ew, rowptr, pos, rec);

    int gblk = (NN + 15) / 16;   // 16 nodes per block (4 waves x 4 nodes)
    gather_kernel<<<gblk, 256, 0, stream>>>(rowptr, rec, msg, aggh);

    upd_kernel<<<nblk, 256, 0, stream>>>(xh, aggh, wt2, bs2, wt3, bs3,
                                         (float*)d_out);
}